// Round 1
// baseline (1406.247 us; speedup 1.0000x reference)
//
#include <hip/hip_runtime.h>
#include <stdint.h>

// ---------------------------------------------------------------------------
// DecoderLayer (B=4, SQ=SK=1024, D=1024, H=16, depth=64, DFF=4096) on gfx950.
// bf16 MFMA GEMMs (16x16x32), f32 accumulation, f32 LN/softmax.
// ---------------------------------------------------------------------------

typedef __attribute__((ext_vector_type(8))) short bf16x8;
typedef __attribute__((ext_vector_type(4))) float f32x4;

typedef const void __attribute__((address_space(1)))* gas_ptr;
typedef void __attribute__((address_space(3)))* las_ptr;

__device__ __forceinline__ ushort f2bf(float f) {
  union { float f; uint32_t u; } x; x.f = f;
  uint32_t r = x.u + 0x7fffu + ((x.u >> 16) & 1u);
  return (ushort)(r >> 16);
}

// ---------------- elementwise convert / transpose / layernorm --------------

__global__ __launch_bounds__(256) void convert_f32_bf16(const float* __restrict__ src,
                                                        ushort* __restrict__ dst, int n4) {
  int i = blockIdx.x * 256 + threadIdx.x;
  if (i < n4) {
    float4 v = ((const float4*)src)[i];
    ushort4 o;
    o.x = f2bf(v.x); o.y = f2bf(v.y); o.z = f2bf(v.z); o.w = f2bf(v.w);
    ((ushort4*)dst)[i] = o;
  }
}

// src [R][C] f32  ->  dst [C][R] bf16   (block (32,8), grid (C/32, R/32))
__global__ __launch_bounds__(256) void transpose_f32_bf16(const float* __restrict__ src,
                                                          ushort* __restrict__ dst,
                                                          int R, int C) {
  __shared__ ushort tile[32][33];
  int c0 = blockIdx.x * 32, r0 = blockIdx.y * 32;
  int tx = threadIdx.x, ty = threadIdx.y;
  for (int i = ty; i < 32; i += 8)
    tile[i][tx] = f2bf(src[(long)(r0 + i) * C + c0 + tx]);
  __syncthreads();
  for (int i = ty; i < 32; i += 8)
    dst[(long)(c0 + i) * R + r0 + tx] = tile[tx][i];
}

// one row (1024 f32) per block, 256 threads x float4
__global__ __launch_bounds__(256) void layernorm_to_bf16(const float* __restrict__ x,
                                                         const float* __restrict__ gamma,
                                                         const float* __restrict__ beta,
                                                         ushort* __restrict__ out) {
  const int row = blockIdx.x;
  const int t = threadIdx.x, lane = t & 63, w = t >> 6;
  float4 v = ((const float4*)(x + (long)row * 1024))[t];
  float s = v.x + v.y + v.z + v.w;
#pragma unroll
  for (int off = 32; off >= 1; off >>= 1) s += __shfl_xor(s, off);
  __shared__ float r1[4], r2[4];
  if (lane == 0) r1[w] = s;
  __syncthreads();
  const float mu = (r1[0] + r1[1] + r1[2] + r1[3]) * (1.f / 1024.f);
  const float dx = v.x - mu, dy = v.y - mu, dz = v.z - mu, dw = v.w - mu;
  float q = dx * dx + dy * dy + dz * dz + dw * dw;
#pragma unroll
  for (int off = 32; off >= 1; off >>= 1) q += __shfl_xor(q, off);
  if (lane == 0) r2[w] = q;
  __syncthreads();
  const float var = (r2[0] + r2[1] + r2[2] + r2[3]) * (1.f / 1024.f);
  const float is = rsqrtf(var + 1e-6f);
  float4 g4 = ((const float4*)gamma)[t];
  float4 b4 = ((const float4*)beta)[t];
  ushort4 o;
  o.x = f2bf(dx * is * g4.x + b4.x);
  o.y = f2bf(dy * is * g4.y + b4.y);
  o.z = f2bf(dz * is * g4.z + b4.z);
  o.w = f2bf(dw * is * g4.w + b4.w);
  ((ushort4*)(out + (long)row * 1024))[t] = o;
}

// ---------------------------- GEMM (B^T form) ------------------------------
// C[M,N] = A[M,K] @ B^T[N,K]^T  (+bias, epilogue variants), bf16 in, f32 acc.
// 256 threads = 4 waves (2x2), tile BM x BN, BK=32, double-buffered LDS with
// global_load_lds width-16 staging; source-address XOR swizzle keeps
// ds_read_b128 fragment reads at <=2-way bank aliasing (free).

constexpr int EPI_BF16 = 0;      // bf16 out row-major
constexpr int EPI_F32RES = 1;    // f32 out = acc + bias + res
constexpr int EPI_HEADS = 2;     // bf16 [B,H,S,64] split-heads store
constexpr int EPI_HEADS_T = 3;   // bf16 [B,H,64,S] transposed (V^T) store
constexpr int EPI_BF16RELU = 4;  // bf16 out with ReLU
constexpr int EPI_CTX = 5;       // bf16 context store [B,S,H*64] (batched z=bh)

template <int BM, int BN, int EPI>
__global__ __launch_bounds__(256) void gemm_bt(const ushort* __restrict__ Aall, long sAz, int lda,
                                               const ushort* __restrict__ Ball, long sBz, int ldb,
                                               const float* __restrict__ bias,
                                               const float* __restrict__ res,
                                               void* __restrict__ outv,
                                               int M, int N, int K) {
  constexpr int BK = 32;
  constexpr int WM = BM / 2, WN = BN / 2;
  constexpr int MR = WM / 16, NR = WN / 16;
  constexpr int ACH = BM * BK / 8;  // # 16B chunks in A tile
  constexpr int BCH = BN * BK / 8;

  const int z = blockIdx.z;
  const ushort* A = Aall + (long)z * sAz;
  const ushort* B = Ball + (long)z * sBz;
  const int m0 = blockIdx.x * BM;
  const int n0 = blockIdx.y * BN;

  __shared__ ushort lds[2][(BM + BN) * BK];

  const int t = threadIdx.x;
  const int lane = t & 63;
  const int w = t >> 6;
  const int wr = w >> 1, wc = w & 1;
  const int g = lane >> 4, rl = lane & 15;
  const int cbase = t & ~63;  // wave-uniform chunk base

  f32x4 acc[MR][NR];
#pragma unroll
  for (int i = 0; i < MR; ++i)
#pragma unroll
    for (int j = 0; j < NR; ++j) {
      f32x4 zv = {0.f, 0.f, 0.f, 0.f};
      acc[i][j] = zv;
    }

  auto stage = [&](int buf, int kt) {
    const int k0 = kt * BK;
#pragma unroll
    for (int j = 0; j < ACH / 256; ++j) {
      const int c = j * 256 + t;
      const int row = c >> 2, pos = c & 3;
      const int kg = pos ^ (row & 3);  // source-address swizzle
      const ushort* src = A + (long)(m0 + row) * lda + k0 + kg * 8;
      ushort* dst = &lds[buf][(j * 256 + cbase) * 8];
      __builtin_amdgcn_global_load_lds((gas_ptr)src, (las_ptr)dst, 16, 0, 0);
    }
#pragma unroll
    for (int j = 0; j < BCH / 256; ++j) {
      const int c = j * 256 + t;
      const int row = c >> 2, pos = c & 3;
      const int kg = pos ^ (row & 3);
      const ushort* src = B + (long)(n0 + row) * ldb + k0 + kg * 8;
      ushort* dst = &lds[buf][BM * BK + (j * 256 + cbase) * 8];
      __builtin_amdgcn_global_load_lds((gas_ptr)src, (las_ptr)dst, 16, 0, 0);
    }
  };

  const int nt = K / BK;
  stage(0, 0);
  asm volatile("s_waitcnt vmcnt(0)" ::: "memory");
  __syncthreads();

  int cur = 0;
  for (int kt = 0; kt < nt; ++kt) {
    if (kt + 1 < nt) stage(cur ^ 1, kt + 1);  // prefetch next tile first
    bf16x8 af[MR], bfr[NR];
#pragma unroll
    for (int i = 0; i < MR; ++i) {
      const int row = wr * WM + i * 16 + rl;
      af[i] = *(const bf16x8*)&lds[cur][row * BK + ((g ^ (row & 3)) * 8)];
    }
#pragma unroll
    for (int j = 0; j < NR; ++j) {
      const int row = wc * WN + j * 16 + rl;
      bfr[j] = *(const bf16x8*)&lds[cur][BM * BK + row * BK + ((g ^ (row & 3)) * 8)];
    }
#pragma unroll
    for (int i = 0; i < MR; ++i)
#pragma unroll
      for (int j = 0; j < NR; ++j)
        acc[i][j] = __builtin_amdgcn_mfma_f32_16x16x32_bf16(af[i], bfr[j], acc[i][j], 0, 0, 0);
    asm volatile("s_waitcnt vmcnt(0)" ::: "memory");
    __syncthreads();
    cur ^= 1;
  }

  const bool hasb = (bias != nullptr);
#pragma unroll
  for (int i = 0; i < MR; ++i) {
#pragma unroll
    for (int j = 0; j < NR; ++j) {
#pragma unroll
      for (int e = 0; e < 4; ++e) {
        const int row = m0 + wr * WM + i * 16 + g * 4 + e;
        const int col = n0 + wc * WN + j * 16 + rl;
        float v = acc[i][j][e];
        if (hasb) v += bias[col];
        if constexpr (EPI == EPI_BF16 || EPI == EPI_BF16RELU) {
          float vv = (EPI == EPI_BF16RELU && v < 0.f) ? 0.f : v;
          ((ushort*)outv)[(long)row * N + col] = f2bf(vv);
        } else if constexpr (EPI == EPI_F32RES) {
          ((float*)outv)[(long)row * N + col] = v + res[(long)row * N + col];
        } else if constexpr (EPI == EPI_HEADS) {
          const int b = row >> 10, s = row & 1023, h = col >> 6, d = col & 63;
          ((ushort*)outv)[(((long)(b * 16 + h) * 1024) + s) * 64 + d] = f2bf(v);
        } else if constexpr (EPI == EPI_HEADS_T) {
          const int b = row >> 10, s = row & 1023, h = col >> 6, d = col & 63;
          ((ushort*)outv)[((long)(b * 16 + h) * 64 + d) * 1024 + s] = f2bf(v);
        } else if constexpr (EPI == EPI_CTX) {
          const int b = z >> 4, h = z & 15;
          ((ushort*)outv)[((long)b * 1024 + row) * 1024 + h * 64 + col] = f2bf(v);
        }
      }
    }
  }
}

// ------------------- fused scores + softmax (per 32 q-rows) ----------------
// grid (SQ/32, B*H), block 512 (8 waves). Wave w computes cols [w*128,w*128+128)
// of scores = Q @ K^T * 0.125 + mask*-1e9 straight from global (K panels are
// L2-resident), then full-row softmax via shuffle + LDS cross-wave reduce.
// Writes attn f32 to d_out chunk and bf16 copy for the AV GEMM.

template <int MODE>  // 0: 2-D padding mask [SQ,SQ]; 1: per-col mask [SK]
__global__ __launch_bounds__(512) void attn_softmax(const ushort* __restrict__ Q,
                                                    const ushort* __restrict__ Kh,
                                                    const float* __restrict__ mask,
                                                    float* __restrict__ outF,
                                                    ushort* __restrict__ outB) {
  const int bh = blockIdx.y;
  const int q0 = blockIdx.x * 32;
  const int t = threadIdx.x, lane = t & 63, w = t >> 6;
  const int g = lane >> 4, rl = lane & 15;
  const ushort* Qb = Q + (long)bh * 65536;
  const ushort* Kb = Kh + (long)bh * 65536;

  bf16x8 qa[2][2];
#pragma unroll
  for (int rb = 0; rb < 2; ++rb)
#pragma unroll
    for (int kk = 0; kk < 2; ++kk)
      qa[rb][kk] = *(const bf16x8*)(Qb + (long)(q0 + rb * 16 + rl) * 64 + kk * 32 + g * 8);

  f32x4 acc[2][8];
#pragma unroll
  for (int rb = 0; rb < 2; ++rb)
#pragma unroll
    for (int nf = 0; nf < 8; ++nf) {
      f32x4 zv = {0.f, 0.f, 0.f, 0.f};
      acc[rb][nf] = zv;
    }

  const int c0 = w * 128;
#pragma unroll
  for (int nf = 0; nf < 8; ++nf) {
    const ushort* kp = Kb + (long)(c0 + nf * 16 + rl) * 64 + g * 8;
    bf16x8 k0 = *(const bf16x8*)(kp);
    bf16x8 k1 = *(const bf16x8*)(kp + 32);
#pragma unroll
    for (int rb = 0; rb < 2; ++rb) {
      acc[rb][nf] = __builtin_amdgcn_mfma_f32_16x16x32_bf16(qa[rb][0], k0, acc[rb][nf], 0, 0, 0);
      acc[rb][nf] = __builtin_amdgcn_mfma_f32_16x16x32_bf16(qa[rb][1], k1, acc[rb][nf], 0, 0, 0);
    }
  }

  // scale + mask
#pragma unroll
  for (int rb = 0; rb < 2; ++rb)
#pragma unroll
    for (int nf = 0; nf < 8; ++nf)
#pragma unroll
      for (int e = 0; e < 4; ++e) {
        const int r = q0 + rb * 16 + g * 4 + e;
        const int c = c0 + nf * 16 + rl;
        float mv;
        if constexpr (MODE == 0) mv = mask[(long)r * 1024 + c];
        else mv = mask[c];
        acc[rb][nf][e] = acc[rb][nf][e] * 0.125f + mv * (-1e9f);
      }

  // per-row max (8 cols per lane -> 16-lane shuffle -> cross-wave LDS)
  __shared__ float redm[8][32];
  __shared__ float reds[8][32];
  float mrow[2][4];
#pragma unroll
  for (int rb = 0; rb < 2; ++rb)
#pragma unroll
    for (int e = 0; e < 4; ++e) {
      float m = acc[rb][0][e];
#pragma unroll
      for (int nf = 1; nf < 8; ++nf) m = fmaxf(m, acc[rb][nf][e]);
#pragma unroll
      for (int off = 8; off >= 1; off >>= 1) m = fmaxf(m, __shfl_xor(m, off));
      mrow[rb][e] = m;
    }
  if (rl == 0) {
#pragma unroll
    for (int rb = 0; rb < 2; ++rb)
#pragma unroll
      for (int e = 0; e < 4; ++e) redm[w][rb * 16 + g * 4 + e] = mrow[rb][e];
  }
  __syncthreads();
  float mfin[2][4];
#pragma unroll
  for (int rb = 0; rb < 2; ++rb)
#pragma unroll
    for (int e = 0; e < 4; ++e) {
      const int r = rb * 16 + g * 4 + e;
      float m = redm[0][r];
#pragma unroll
      for (int ww = 1; ww < 8; ++ww) m = fmaxf(m, redm[ww][r]);
      mfin[rb][e] = m;
    }

  // exp + per-row sum
  float srow[2][4];
#pragma unroll
  for (int rb = 0; rb < 2; ++rb)
#pragma unroll
    for (int e = 0; e < 4; ++e) {
      float s = 0.f;
#pragma unroll
      for (int nf = 0; nf < 8; ++nf) {
        float p = exp2f((acc[rb][nf][e] - mfin[rb][e]) * 1.44269504088896340736f);
        acc[rb][nf][e] = p;
        s += p;
      }
#pragma unroll
      for (int off = 8; off >= 1; off >>= 1) s += __shfl_xor(s, off);
      srow[rb][e] = s;
    }
  if (rl == 0) {
#pragma unroll
    for (int rb = 0; rb < 2; ++rb)
#pragma unroll
      for (int e = 0; e < 4; ++e) reds[w][rb * 16 + g * 4 + e] = srow[rb][e];
  }
  __syncthreads();

#pragma unroll
  for (int rb = 0; rb < 2; ++rb)
#pragma unroll
    for (int e = 0; e < 4; ++e) {
      const int r = rb * 16 + g * 4 + e;
      float s = 0.f;
#pragma unroll
      for (int ww = 0; ww < 8; ++ww) s += reds[ww][r];
      const float inv = 1.0f / s;
      const long rowoff = (long)bh * 1048576 + (long)(q0 + r) * 1024;
#pragma unroll
      for (int nf = 0; nf < 8; ++nf) {
        const int c = c0 + nf * 16 + rl;
        const float p = acc[rb][nf][e] * inv;
        outF[rowoff + c] = p;
        outB[rowoff + c] = f2bf(p);
      }
    }
}

// ---------------------------------------------------------------------------

extern "C" void kernel_launch(void* const* d_in, const int* in_sizes, int n_in,
                              void* d_out, int out_size, void* d_ws, size_t ws_size,
                              hipStream_t stream) {
  (void)in_sizes; (void)n_in; (void)out_size; (void)ws_size;

  const float* x     = (const float*)d_in[0];
  const float* y     = (const float*)d_in[1];
  const float* cmask = (const float*)d_in[2];
  const float* pmask = (const float*)d_in[3];
  const float* sa_wq = (const float*)d_in[4];
  const float* sa_bq = (const float*)d_in[5];
  const float* sa_wk = (const float*)d_in[6];
  const float* sa_bk = (const float*)d_in[7];
  const float* sa_wv = (const float*)d_in[8];
  const float* sa_bv = (const float*)d_in[9];
  const float* sa_wo = (const float*)d_in[10];
  const float* sa_bo = (const float*)d_in[11];
  const float* ca_wq = (const float*)d_in[12];
  const float* ca_bq = (const float*)d_in[13];
  const float* ca_wk = (const float*)d_in[14];
  const float* ca_bk = (const float*)d_in[15];
  const float* ca_wv = (const float*)d_in[16];
  const float* ca_bv = (const float*)d_in[17];
  const float* ca_wo = (const float*)d_in[18];
  const float* ca_bo = (const float*)d_in[19];
  const float* ffn_w1 = (const float*)d_in[20];
  const float* ffn_b1 = (const float*)d_in[21];
  const float* ffn_w2 = (const float*)d_in[22];
  const float* ffn_b2 = (const float*)d_in[23];
  const float* ln1_g = (const float*)d_in[24];
  const float* ln1_b = (const float*)d_in[25];
  const float* ln2_g = (const float*)d_in[26];
  const float* ln2_b = (const float*)d_in[27];
  const float* ln3_g = (const float*)d_in[28];
  const float* ln3_b = (const float*)d_in[29];

  char* ws = (char*)d_ws;
  ushort* wT0 = (ushort*)(ws + 0);          // 8 x [1024][1024] bf16 (W^T)
  ushort* w1T = (ushort*)(ws + 16777216);   // [4096][1024] bf16
  ushort* w2T = (ushort*)(ws + 25165824);   // [1024][4096] bf16
  ushort* ybf = (ushort*)(ws + 33554432);   // y bf16 [4096][1024]
  ushort* lnb = (ushort*)(ws + 41943040);   // LN output bf16 (reused x3)
  ushort* Qh  = (ushort*)(ws + 50331648);   // [BH][1024][64]
  ushort* Kh  = (ushort*)(ws + 58720256);   // [BH][1024][64]
  ushort* VhT = (ushort*)(ws + 67108864);   // [BH][64][1024]
  ushort* ctx = (ushort*)(ws + 75497472);   // [4096][1024] bf16
  float*  out1 = (float*)(ws + 83886080);   // residual stream after SA
  float*  out2 = (float*)(ws + 100663296);  // residual stream after CA
  ushort* hbuf = (ushort*)(ws + 117440512); // FFN hidden [4096][4096] bf16
  ushort* attnb = (ushort*)(ws + 150994944);// attn probs bf16 [BH][1024][1024]

  float* out0   = (float*)d_out;
  float* attnF1 = out0 + 4194304;    // dec_attn     [4,16,1024,1024]
  float* attnF2 = out0 + 71303168;   // dec_enc_attn [4,16,1024,1024]

  // ---- weight/activation conversions ----
  convert_f32_bf16<<<dim3(4096), dim3(256), 0, stream>>>(y, ybf, 1048576);
  const float* wsrc[8] = {sa_wq, sa_wk, sa_wv, sa_wo, ca_wq, ca_wk, ca_wv, ca_wo};
  for (int i = 0; i < 8; ++i)
    transpose_f32_bf16<<<dim3(32, 32), dim3(32, 8), 0, stream>>>(wsrc[i], wT0 + (long)i * 1048576, 1024, 1024);
  transpose_f32_bf16<<<dim3(128, 32), dim3(32, 8), 0, stream>>>(ffn_w1, w1T, 1024, 4096);
  transpose_f32_bf16<<<dim3(32, 128), dim3(32, 8), 0, stream>>>(ffn_w2, w2T, 4096, 1024);

  // ---- self-attention sub-layer ----
  layernorm_to_bf16<<<dim3(4096), dim3(256), 0, stream>>>(x, ln1_g, ln1_b, lnb);

  gemm_bt<128, 128, EPI_HEADS><<<dim3(32, 8, 1), dim3(256), 0, stream>>>(
      lnb, 0L, 1024, wT0 + 0L * 1048576, 0L, 1024, sa_bq, nullptr, Qh, 4096, 1024, 1024);
  gemm_bt<128, 128, EPI_HEADS><<<dim3(32, 8, 1), dim3(256), 0, stream>>>(
      lnb, 0L, 1024, wT0 + 1L * 1048576, 0L, 1024, sa_bk, nullptr, Kh, 4096, 1024, 1024);
  gemm_bt<128, 128, EPI_HEADS_T><<<dim3(32, 8, 1), dim3(256), 0, stream>>>(
      lnb, 0L, 1024, wT0 + 2L * 1048576, 0L, 1024, sa_bv, nullptr, VhT, 4096, 1024, 1024);

  attn_softmax<0><<<dim3(32, 64), dim3(512), 0, stream>>>(Qh, Kh, pmask, attnF1, attnb);

  gemm_bt<128, 64, EPI_CTX><<<dim3(8, 1, 64), dim3(256), 0, stream>>>(
      attnb, 1048576L, 1024, VhT, 65536L, 1024, nullptr, nullptr, ctx, 1024, 64, 1024);

  gemm_bt<128, 128, EPI_F32RES><<<dim3(32, 8, 1), dim3(256), 0, stream>>>(
      ctx, 0L, 1024, wT0 + 3L * 1048576, 0L, 1024, sa_bo, x, out1, 4096, 1024, 1024);

  // ---- cross-attention sub-layer ----
  layernorm_to_bf16<<<dim3(4096), dim3(256), 0, stream>>>(out1, ln2_g, ln2_b, lnb);

  gemm_bt<128, 128, EPI_HEADS><<<dim3(32, 8, 1), dim3(256), 0, stream>>>(
      lnb, 0L, 1024, wT0 + 4L * 1048576, 0L, 1024, ca_bq, nullptr, Qh, 4096, 1024, 1024);
  gemm_bt<128, 128, EPI_HEADS><<<dim3(32, 8, 1), dim3(256), 0, stream>>>(
      ybf, 0L, 1024, wT0 + 5L * 1048576, 0L, 1024, ca_bk, nullptr, Kh, 4096, 1024, 1024);
  gemm_bt<128, 128, EPI_HEADS_T><<<dim3(32, 8, 1), dim3(256), 0, stream>>>(
      ybf, 0L, 1024, wT0 + 6L * 1048576, 0L, 1024, ca_bv, nullptr, VhT, 4096, 1024, 1024);

  attn_softmax<1><<<dim3(32, 64), dim3(512), 0, stream>>>(Qh, Kh, cmask, attnF2, attnb);

  gemm_bt<128, 64, EPI_CTX><<<dim3(8, 1, 64), dim3(256), 0, stream>>>(
      attnb, 1048576L, 1024, VhT, 65536L, 1024, nullptr, nullptr, ctx, 1024, 64, 1024);

  gemm_bt<128, 128, EPI_F32RES><<<dim3(32, 8, 1), dim3(256), 0, stream>>>(
      ctx, 0L, 1024, wT0 + 7L * 1048576, 0L, 1024, ca_bo, out1, out2, 4096, 1024, 1024);

  // ---- FFN sub-layer ----
  layernorm_to_bf16<<<dim3(4096), dim3(256), 0, stream>>>(out2, ln3_g, ln3_b, lnb);

  gemm_bt<128, 128, EPI_BF16RELU><<<dim3(32, 32, 1), dim3(256), 0, stream>>>(
      lnb, 0L, 1024, w1T, 0L, 1024, ffn_b1, nullptr, hbuf, 4096, 4096, 1024);

  gemm_bt<128, 128, EPI_F32RES><<<dim3(32, 8, 1), dim3(256), 0, stream>>>(
      hbuf, 0L, 4096, w2T, 0L, 4096, ffn_b2, out2, out0, 4096, 1024, 4096);
}

// Round 2
// 1211.819 us; speedup vs baseline: 1.1604x; 1.1604x over previous
//
#include <hip/hip_runtime.h>
#include <stdint.h>

// ---------------------------------------------------------------------------
// DecoderLayer (B=4, SQ=SK=1024, D=1024, H=16, depth=64, DFF=4096) on gfx950.
// bf16 MFMA GEMMs (16x16x32), f32 accumulation, f32 LN/softmax.
// R2: fused QKV (grid.z=3), fused softmax+PV (ctx direct), split-K atomic
//     GEMMs for O-proj / FFN2 to fix 1-block/CU occupancy.
// ---------------------------------------------------------------------------

typedef __attribute__((ext_vector_type(8))) short bf16x8;
typedef __attribute__((ext_vector_type(4))) float f32x4;

typedef const void __attribute__((address_space(1)))* gas_ptr;
typedef void __attribute__((address_space(3)))* las_ptr;

__device__ __forceinline__ ushort f2bf(float f) {
  union { float f; uint32_t u; } x; x.f = f;
  uint32_t r = x.u + 0x7fffu + ((x.u >> 16) & 1u);
  return (ushort)(r >> 16);
}

// ---------------- elementwise convert / transpose / layernorm --------------

__global__ __launch_bounds__(256) void convert_f32_bf16(const float* __restrict__ src,
                                                        ushort* __restrict__ dst, int n4) {
  int i = blockIdx.x * 256 + threadIdx.x;
  if (i < n4) {
    float4 v = ((const float4*)src)[i];
    ushort4 o;
    o.x = f2bf(v.x); o.y = f2bf(v.y); o.z = f2bf(v.z); o.w = f2bf(v.w);
    ((ushort4*)dst)[i] = o;
  }
}

// src [R][C] f32  ->  dst [C][R] bf16   (block (32,8), grid (C/32, R/32))
__global__ __launch_bounds__(256) void transpose_f32_bf16(const float* __restrict__ src,
                                                          ushort* __restrict__ dst,
                                                          int R, int C) {
  __shared__ ushort tile[32][33];
  int c0 = blockIdx.x * 32, r0 = blockIdx.y * 32;
  int tx = threadIdx.x, ty = threadIdx.y;
  for (int i = ty; i < 32; i += 8)
    tile[i][tx] = f2bf(src[(long)(r0 + i) * C + c0 + tx]);
  __syncthreads();
  for (int i = ty; i < 32; i += 8)
    dst[(long)(c0 + i) * R + r0 + tx] = tile[tx][i];
}

// one row (1024 f32) per block, 256 threads x float4
__global__ __launch_bounds__(256) void layernorm_to_bf16(const float* __restrict__ x,
                                                         const float* __restrict__ gamma,
                                                         const float* __restrict__ beta,
                                                         ushort* __restrict__ out) {
  const int row = blockIdx.x;
  const int t = threadIdx.x, lane = t & 63, w = t >> 6;
  float4 v = ((const float4*)(x + (long)row * 1024))[t];
  float s = v.x + v.y + v.z + v.w;
#pragma unroll
  for (int off = 32; off >= 1; off >>= 1) s += __shfl_xor(s, off);
  __shared__ float r1[4], r2[4];
  if (lane == 0) r1[w] = s;
  __syncthreads();
  const float mu = (r1[0] + r1[1] + r1[2] + r1[3]) * (1.f / 1024.f);
  const float dx = v.x - mu, dy = v.y - mu, dz = v.z - mu, dw = v.w - mu;
  float q = dx * dx + dy * dy + dz * dz + dw * dw;
#pragma unroll
  for (int off = 32; off >= 1; off >>= 1) q += __shfl_xor(q, off);
  if (lane == 0) r2[w] = q;
  __syncthreads();
  const float var = (r2[0] + r2[1] + r2[2] + r2[3]) * (1.f / 1024.f);
  const float is = rsqrtf(var + 1e-6f);
  float4 g4 = ((const float4*)gamma)[t];
  float4 b4 = ((const float4*)beta)[t];
  ushort4 o;
  o.x = f2bf(dx * is * g4.x + b4.x);
  o.y = f2bf(dy * is * g4.y + b4.y);
  o.z = f2bf(dz * is * g4.z + b4.z);
  o.w = f2bf(dw * is * g4.w + b4.w);
  ((ushort4*)(out + (long)row * 1024))[t] = o;
}

// out[i] = res[i] + bias[col]   (f32, row length 1024, float4-vectorized)
__global__ __launch_bounds__(256) void init_bias_res(const float* __restrict__ res,
                                                     const float* __restrict__ bias,
                                                     float* __restrict__ out, int n4) {
  int i = blockIdx.x * 256 + threadIdx.x;
  if (i < n4) {
    float4 r = ((const float4*)res)[i];
    float4 b = ((const float4*)bias)[i & 255];
    float4 o = {r.x + b.x, r.y + b.y, r.z + b.z, r.w + b.w};
    ((float4*)out)[i] = o;
  }
}

// ---------------------------- GEMM (B^T form) ------------------------------

constexpr int EPI_BF16 = 0;      // bf16 out row-major
constexpr int EPI_F32RES = 1;    // f32 out = acc + bias + res
constexpr int EPI_BF16RELU = 4;  // bf16 out with ReLU
constexpr int EPI_ATOMIC = 6;    // f32 atomicAdd (split-K; bias must be null)

template <int BM, int BN, int EPI>
__global__ __launch_bounds__(256) void gemm_bt(const ushort* __restrict__ Aall, long sAz, int lda,
                                               const ushort* __restrict__ Ball, long sBz, int ldb,
                                               const float* __restrict__ bias,
                                               const float* __restrict__ res,
                                               void* __restrict__ outv,
                                               int M, int N, int K) {
  constexpr int BK = 32;
  constexpr int WM = BM / 2, WN = BN / 2;
  constexpr int MR = WM / 16, NR = WN / 16;
  constexpr int ACH = BM * BK / 8;
  constexpr int BCH = BN * BK / 8;

  const int z = blockIdx.z;
  const ushort* A = Aall + (long)z * sAz;
  const ushort* B = Ball + (long)z * sBz;
  const int m0 = blockIdx.x * BM;
  const int n0 = blockIdx.y * BN;

  __shared__ ushort lds[2][(BM + BN) * BK];

  const int t = threadIdx.x;
  const int lane = t & 63;
  const int w = t >> 6;
  const int wr = w >> 1, wc = w & 1;
  const int g = lane >> 4, rl = lane & 15;
  const int cbase = t & ~63;

  f32x4 acc[MR][NR];
#pragma unroll
  for (int i = 0; i < MR; ++i)
#pragma unroll
    for (int j = 0; j < NR; ++j) {
      f32x4 zv = {0.f, 0.f, 0.f, 0.f};
      acc[i][j] = zv;
    }

  auto stage = [&](int buf, int kt) {
    const int k0 = kt * BK;
#pragma unroll
    for (int j = 0; j < ACH / 256; ++j) {
      const int c = j * 256 + t;
      const int row = c >> 2, pos = c & 3;
      const int kg = pos ^ (row & 3);
      const ushort* src = A + (long)(m0 + row) * lda + k0 + kg * 8;
      ushort* dst = &lds[buf][(j * 256 + cbase) * 8];
      __builtin_amdgcn_global_load_lds((gas_ptr)src, (las_ptr)dst, 16, 0, 0);
    }
#pragma unroll
    for (int j = 0; j < BCH / 256; ++j) {
      const int c = j * 256 + t;
      const int row = c >> 2, pos = c & 3;
      const int kg = pos ^ (row & 3);
      const ushort* src = B + (long)(n0 + row) * ldb + k0 + kg * 8;
      ushort* dst = &lds[buf][BM * BK + (j * 256 + cbase) * 8];
      __builtin_amdgcn_global_load_lds((gas_ptr)src, (las_ptr)dst, 16, 0, 0);
    }
  };

  const int nt = K / BK;
  stage(0, 0);
  asm volatile("s_waitcnt vmcnt(0)" ::: "memory");
  __syncthreads();

  int cur = 0;
  for (int kt = 0; kt < nt; ++kt) {
    if (kt + 1 < nt) stage(cur ^ 1, kt + 1);
    bf16x8 af[MR], bfr[NR];
#pragma unroll
    for (int i = 0; i < MR; ++i) {
      const int row = wr * WM + i * 16 + rl;
      af[i] = *(const bf16x8*)&lds[cur][row * BK + ((g ^ (row & 3)) * 8)];
    }
#pragma unroll
    for (int j = 0; j < NR; ++j) {
      const int row = wc * WN + j * 16 + rl;
      bfr[j] = *(const bf16x8*)&lds[cur][BM * BK + row * BK + ((g ^ (row & 3)) * 8)];
    }
#pragma unroll
    for (int i = 0; i < MR; ++i)
#pragma unroll
      for (int j = 0; j < NR; ++j)
        acc[i][j] = __builtin_amdgcn_mfma_f32_16x16x32_bf16(af[i], bfr[j], acc[i][j], 0, 0, 0);
    asm volatile("s_waitcnt vmcnt(0)" ::: "memory");
    __syncthreads();
    cur ^= 1;
  }

  const bool hasb = (bias != nullptr);
#pragma unroll
  for (int i = 0; i < MR; ++i) {
#pragma unroll
    for (int j = 0; j < NR; ++j) {
#pragma unroll
      for (int e = 0; e < 4; ++e) {
        const int row = m0 + wr * WM + i * 16 + g * 4 + e;
        const int col = n0 + wc * WN + j * 16 + rl;
        float v = acc[i][j][e];
        if (hasb) v += bias[col];
        if constexpr (EPI == EPI_BF16 || EPI == EPI_BF16RELU) {
          float vv = (EPI == EPI_BF16RELU && v < 0.f) ? 0.f : v;
          ((ushort*)outv)[(long)row * N + col] = f2bf(vv);
        } else if constexpr (EPI == EPI_F32RES) {
          ((float*)outv)[(long)row * N + col] = v + res[(long)row * N + col];
        } else if constexpr (EPI == EPI_ATOMIC) {
          atomicAdd(&((float*)outv)[(long)row * N + col], v);
        }
      }
    }
  }
}

// ----------------------- fused QKV projection ------------------------------
// grid (32, 8, 3): z=0 -> Q (A=Aq), z=1 -> K, z=2 -> V^T store. B = Wt+z*1M.

template <bool CROSS>
__global__ __launch_bounds__(256) void qkv_proj(const ushort* __restrict__ Aq,
                                                const ushort* __restrict__ Akv,
                                                const ushort* __restrict__ Wt,
                                                const float* __restrict__ bq,
                                                const float* __restrict__ bk,
                                                const float* __restrict__ bv,
                                                ushort* __restrict__ Qh,
                                                ushort* __restrict__ Kh,
                                                ushort* __restrict__ VhT) {
  constexpr int BM = 128, BN = 128, BK = 32;
  constexpr int MR = 4, NR = 4;

  const int z = blockIdx.z;
  const ushort* A = (CROSS && z > 0) ? Akv : Aq;
  const ushort* B = Wt + (long)z * 1048576;
  const float* bias = (z == 0) ? bq : (z == 1) ? bk : bv;
  const int m0 = blockIdx.x * BM;
  const int n0 = blockIdx.y * BN;

  __shared__ ushort lds[2][(BM + BN) * BK];

  const int t = threadIdx.x;
  const int lane = t & 63;
  const int w = t >> 6;
  const int wr = w >> 1, wc = w & 1;
  const int g = lane >> 4, rl = lane & 15;
  const int cbase = t & ~63;

  f32x4 acc[MR][NR];
#pragma unroll
  for (int i = 0; i < MR; ++i)
#pragma unroll
    for (int j = 0; j < NR; ++j) {
      f32x4 zv = {0.f, 0.f, 0.f, 0.f};
      acc[i][j] = zv;
    }

  auto stage = [&](int buf, int kt) {
    const int k0 = kt * BK;
    {
      const int row = t >> 2, pos = t & 3;
      const int kg = pos ^ (row & 3);
      const ushort* srcA = A + (long)(m0 + row) * 1024 + k0 + kg * 8;
      __builtin_amdgcn_global_load_lds((gas_ptr)srcA, (las_ptr)&lds[buf][cbase * 8], 16, 0, 0);
      const int c2 = 256 + t;
      const int row2 = c2 >> 2, pos2 = c2 & 3;
      const int kg2 = pos2 ^ (row2 & 3);
      const ushort* srcA2 = A + (long)(m0 + row2) * 1024 + k0 + kg2 * 8;
      __builtin_amdgcn_global_load_lds((gas_ptr)srcA2, (las_ptr)&lds[buf][(256 + cbase) * 8], 16, 0, 0);
      const ushort* srcB = B + (long)(n0 + row) * 1024 + k0 + kg * 8;
      __builtin_amdgcn_global_load_lds((gas_ptr)srcB, (las_ptr)&lds[buf][4096 + cbase * 8], 16, 0, 0);
      const ushort* srcB2 = B + (long)(n0 + row2) * 1024 + k0 + kg2 * 8;
      __builtin_amdgcn_global_load_lds((gas_ptr)srcB2, (las_ptr)&lds[buf][4096 + (256 + cbase) * 8], 16, 0, 0);
    }
  };

  stage(0, 0);
  asm volatile("s_waitcnt vmcnt(0)" ::: "memory");
  __syncthreads();

  int cur = 0;
  for (int kt = 0; kt < 32; ++kt) {
    if (kt + 1 < 32) stage(cur ^ 1, kt + 1);
    bf16x8 af[MR], bfr[NR];
#pragma unroll
    for (int i = 0; i < MR; ++i) {
      const int row = wr * 64 + i * 16 + rl;
      af[i] = *(const bf16x8*)&lds[cur][row * BK + ((g ^ (row & 3)) * 8)];
    }
#pragma unroll
    for (int j = 0; j < NR; ++j) {
      const int row = wc * 64 + j * 16 + rl;
      bfr[j] = *(const bf16x8*)&lds[cur][4096 + row * BK + ((g ^ (row & 3)) * 8)];
    }
#pragma unroll
    for (int i = 0; i < MR; ++i)
#pragma unroll
      for (int j = 0; j < NR; ++j)
        acc[i][j] = __builtin_amdgcn_mfma_f32_16x16x32_bf16(af[i], bfr[j], acc[i][j], 0, 0, 0);
    asm volatile("s_waitcnt vmcnt(0)" ::: "memory");
    __syncthreads();
    cur ^= 1;
  }

  ushort* out = (z == 0) ? Qh : (z == 1) ? Kh : VhT;
#pragma unroll
  for (int i = 0; i < MR; ++i) {
#pragma unroll
    for (int j = 0; j < NR; ++j) {
#pragma unroll
      for (int e = 0; e < 4; ++e) {
        const int row = m0 + wr * 64 + i * 16 + g * 4 + e;
        const int col = n0 + wc * 64 + j * 16 + rl;
        const float v = acc[i][j][e] + bias[col];
        const int b = row >> 10, s = row & 1023, h = col >> 6, d = col & 63;
        if (z < 2)
          out[(((long)(b * 16 + h) * 1024) + s) * 64 + d] = f2bf(v);
        else
          out[((long)(b * 16 + h) * 64 + d) * 1024 + s] = f2bf(v);
      }
    }
  }
}

// -------------- fused scores + softmax + PV (per 32 q-rows) ----------------
// grid (SQ/32, B*H), block 512 (8 waves). Wave w: cols [w*128, w*128+128).
// After softmax, P goes to a swizzled LDS tile; each wave computes a 32x64
// PV partial over its own 128-col K-strip (V^T B-fragments from L2), then
// cross-wave LDS reduction produces the ctx tile directly.

__device__ __forceinline__ int p_off(int r, int p) {  // ushort offset of 16B chunk
  return (r * 128 + (p ^ (r & 7))) * 8;
}

template <int MODE>  // 0: 2-D padding mask [SQ,SQ]; 1: per-col mask [SK]
__global__ __launch_bounds__(512) void attn_softmax_pv(const ushort* __restrict__ Q,
                                                       const ushort* __restrict__ Kh,
                                                       const ushort* __restrict__ VhT,
                                                       const float* __restrict__ mask,
                                                       float* __restrict__ outF,
                                                       ushort* __restrict__ ctx) {
  const int bh = blockIdx.y;
  const int q0 = blockIdx.x * 32;
  const int t = threadIdx.x, lane = t & 63, w = t >> 6;
  const int g = lane >> 4, rl = lane & 15;
  const ushort* Qb = Q + (long)bh * 65536;
  const ushort* Kb = Kh + (long)bh * 65536;
  const ushort* Vb = VhT + (long)bh * 65536;

  __shared__ ushort Pl[32768];  // 64 KB: P tile (bf16, swizzled) then f32 partials
  __shared__ float redm[8][32];
  __shared__ float reds[8][32];

  bf16x8 qa[2][2];
#pragma unroll
  for (int rb = 0; rb < 2; ++rb)
#pragma unroll
    for (int kk = 0; kk < 2; ++kk)
      qa[rb][kk] = *(const bf16x8*)(Qb + (long)(q0 + rb * 16 + rl) * 64 + kk * 32 + g * 8);

  f32x4 acc[2][8];
#pragma unroll
  for (int rb = 0; rb < 2; ++rb)
#pragma unroll
    for (int nf = 0; nf < 8; ++nf) {
      f32x4 zv = {0.f, 0.f, 0.f, 0.f};
      acc[rb][nf] = zv;
    }

  const int c0 = w * 128;
#pragma unroll
  for (int nf = 0; nf < 8; ++nf) {
    const ushort* kp = Kb + (long)(c0 + nf * 16 + rl) * 64 + g * 8;
    bf16x8 k0 = *(const bf16x8*)(kp);
    bf16x8 k1 = *(const bf16x8*)(kp + 32);
#pragma unroll
    for (int rb = 0; rb < 2; ++rb) {
      acc[rb][nf] = __builtin_amdgcn_mfma_f32_16x16x32_bf16(qa[rb][0], k0, acc[rb][nf], 0, 0, 0);
      acc[rb][nf] = __builtin_amdgcn_mfma_f32_16x16x32_bf16(qa[rb][1], k1, acc[rb][nf], 0, 0, 0);
    }
  }

  // scale + mask
#pragma unroll
  for (int rb = 0; rb < 2; ++rb)
#pragma unroll
    for (int nf = 0; nf < 8; ++nf)
#pragma unroll
      for (int e = 0; e < 4; ++e) {
        const int r = q0 + rb * 16 + g * 4 + e;
        const int c = c0 + nf * 16 + rl;
        float mv;
        if constexpr (MODE == 0) mv = mask[(long)r * 1024 + c];
        else mv = mask[c];
        acc[rb][nf][e] = acc[rb][nf][e] * 0.125f + mv * (-1e9f);
      }

  // row max
  float mrow[2][4];
#pragma unroll
  for (int rb = 0; rb < 2; ++rb)
#pragma unroll
    for (int e = 0; e < 4; ++e) {
      float m = acc[rb][0][e];
#pragma unroll
      for (int nf = 1; nf < 8; ++nf) m = fmaxf(m, acc[rb][nf][e]);
#pragma unroll
      for (int off = 8; off >= 1; off >>= 1) m = fmaxf(m, __shfl_xor(m, off));
      mrow[rb][e] = m;
    }
  if (rl == 0)
#pragma unroll
    for (int rb = 0; rb < 2; ++rb)
#pragma unroll
      for (int e = 0; e < 4; ++e) redm[w][rb * 16 + g * 4 + e] = mrow[rb][e];
  __syncthreads();
  float mfin[2][4];
#pragma unroll
  for (int rb = 0; rb < 2; ++rb)
#pragma unroll
    for (int e = 0; e < 4; ++e) {
      const int r = rb * 16 + g * 4 + e;
      float m = redm[0][r];
#pragma unroll
      for (int ww = 1; ww < 8; ++ww) m = fmaxf(m, redm[ww][r]);
      mfin[rb][e] = m;
    }

  // exp + row sum
  float srow[2][4];
#pragma unroll
  for (int rb = 0; rb < 2; ++rb)
#pragma unroll
    for (int e = 0; e < 4; ++e) {
      float s = 0.f;
#pragma unroll
      for (int nf = 0; nf < 8; ++nf) {
        float p = exp2f((acc[rb][nf][e] - mfin[rb][e]) * 1.44269504088896340736f);
        acc[rb][nf][e] = p;
        s += p;
      }
#pragma unroll
      for (int off = 8; off >= 1; off >>= 1) s += __shfl_xor(s, off);
      srow[rb][e] = s;
    }
  if (rl == 0)
#pragma unroll
    for (int rb = 0; rb < 2; ++rb)
#pragma unroll
      for (int e = 0; e < 4; ++e) reds[w][rb * 16 + g * 4 + e] = srow[rb][e];
  __syncthreads();

  // normalize, write f32 attn to d_out, and bf16 P to swizzled LDS
#pragma unroll
  for (int rb = 0; rb < 2; ++rb)
#pragma unroll
    for (int e = 0; e < 4; ++e) {
      const int r = rb * 16 + g * 4 + e;
      float s = 0.f;
#pragma unroll
      for (int ww = 0; ww < 8; ++ww) s += reds[ww][r];
      const float inv = 1.0f / s;
      const long rowoff = (long)bh * 1048576 + (long)(q0 + r) * 1024;
#pragma unroll
      for (int nf = 0; nf < 8; ++nf) {
        const int c = c0 + nf * 16 + rl;
        const float p = acc[rb][nf][e] * inv;
        outF[rowoff + c] = p;
        Pl[p_off(r, c >> 3) + (c & 7)] = f2bf(p);
      }
    }
  __syncthreads();

  // PV partial: wave w covers K-strip [c0, c0+128)
  f32x4 acc2[2][4];
#pragma unroll
  for (int rb = 0; rb < 2; ++rb)
#pragma unroll
    for (int j = 0; j < 4; ++j) {
      f32x4 zv = {0.f, 0.f, 0.f, 0.f};
      acc2[rb][j] = zv;
    }
#pragma unroll
  for (int s = 0; s < 4; ++s) {
    const int kb = c0 + s * 32;
    bf16x8 a[2];
#pragma unroll
    for (int rb = 0; rb < 2; ++rb)
      a[rb] = *(const bf16x8*)&Pl[p_off(rb * 16 + rl, (kb >> 3) + g)];
#pragma unroll
    for (int j = 0; j < 4; ++j) {
      bf16x8 b = *(const bf16x8*)(Vb + (long)(j * 16 + rl) * 1024 + kb + g * 8);
#pragma unroll
      for (int rb = 0; rb < 2; ++rb)
        acc2[rb][j] = __builtin_amdgcn_mfma_f32_16x16x32_bf16(a[rb], b, acc2[rb][j], 0, 0, 0);
    }
  }
  __syncthreads();  // all P reads done before partials overwrite Pl

  float* Pred = (float*)Pl;  // [8][32*64]
#pragma unroll
  for (int rb = 0; rb < 2; ++rb)
#pragma unroll
    for (int j = 0; j < 4; ++j)
#pragma unroll
      for (int e = 0; e < 4; ++e) {
        const int r = rb * 16 + g * 4 + e;
        const int d = j * 16 + rl;
        Pred[w * 2048 + r * 64 + d] = acc2[rb][j][e];
      }
  __syncthreads();

  const int bb = bh >> 4, hh = bh & 15;
#pragma unroll
  for (int i = t; i < 2048; i += 512) {
    float s = 0.f;
#pragma unroll
    for (int ww = 0; ww < 8; ++ww) s += Pred[ww * 2048 + i];
    const int r = i >> 6, d = i & 63;
    ctx[((long)bb * 1024 + q0 + r) * 1024 + hh * 64 + d] = f2bf(s);
  }
}

// ---------------------------------------------------------------------------

extern "C" void kernel_launch(void* const* d_in, const int* in_sizes, int n_in,
                              void* d_out, int out_size, void* d_ws, size_t ws_size,
                              hipStream_t stream) {
  (void)in_sizes; (void)n_in; (void)out_size; (void)ws_size;

  const float* x     = (const float*)d_in[0];
  const float* y     = (const float*)d_in[1];
  const float* cmask = (const float*)d_in[2];
  const float* pmask = (const float*)d_in[3];
  const float* sa_wq = (const float*)d_in[4];
  const float* sa_bq = (const float*)d_in[5];
  const float* sa_wk = (const float*)d_in[6];
  const float* sa_bk = (const float*)d_in[7];
  const float* sa_wv = (const float*)d_in[8];
  const float* sa_bv = (const float*)d_in[9];
  const float* sa_wo = (const float*)d_in[10];
  const float* sa_bo = (const float*)d_in[11];
  const float* ca_wq = (const float*)d_in[12];
  const float* ca_bq = (const float*)d_in[13];
  const float* ca_wk = (const float*)d_in[14];
  const float* ca_bk = (const float*)d_in[15];
  const float* ca_wv = (const float*)d_in[16];
  const float* ca_bv = (const float*)d_in[17];
  const float* ca_wo = (const float*)d_in[18];
  const float* ca_bo = (const float*)d_in[19];
  const float* ffn_w1 = (const float*)d_in[20];
  const float* ffn_b1 = (const float*)d_in[21];
  const float* ffn_w2 = (const float*)d_in[22];
  const float* ffn_b2 = (const float*)d_in[23];
  const float* ln1_g = (const float*)d_in[24];
  const float* ln1_b = (const float*)d_in[25];
  const float* ln2_g = (const float*)d_in[26];
  const float* ln2_b = (const float*)d_in[27];
  const float* ln3_g = (const float*)d_in[28];
  const float* ln3_b = (const float*)d_in[29];

  char* ws = (char*)d_ws;
  ushort* wT0 = (ushort*)(ws + 0);           // 8 x [1024][1024] bf16 (W^T)
  ushort* w1T = (ushort*)(ws + (16L << 20)); // [4096][1024]
  ushort* w2T = (ushort*)(ws + (24L << 20)); // [1024][4096]
  ushort* ybf = (ushort*)(ws + (32L << 20)); // y bf16
  ushort* lnb = (ushort*)(ws + (40L << 20)); // LN output bf16 (reused x3)
  ushort* Qh  = (ushort*)(ws + (48L << 20)); // [BH][1024][64]
  ushort* Kh  = (ushort*)(ws + (56L << 20)); // [BH][1024][64]
  ushort* VhT = (ushort*)(ws + (64L << 20)); // [BH][64][1024]
  ushort* ctx = (ushort*)(ws + (72L << 20)); // [4096][1024] bf16
  float*  out1 = (float*)(ws + (80L << 20)); // residual stream after SA
  float*  out2 = (float*)(ws + (96L << 20)); // residual stream after CA
  ushort* hbuf = (ushort*)(ws + (112L << 20)); // FFN hidden [4096][4096] bf16

  float* out0   = (float*)d_out;
  float* attnF1 = out0 + 4194304;    // dec_attn     [4,16,1024,1024]
  float* attnF2 = out0 + 71303168;   // dec_enc_attn [4,16,1024,1024]

  // ---- weight/activation conversions ----
  convert_f32_bf16<<<dim3(4096), dim3(256), 0, stream>>>(y, ybf, 1048576);
  const float* wsrc[8] = {sa_wq, sa_wk, sa_wv, sa_wo, ca_wq, ca_wk, ca_wv, ca_wo};
  for (int i = 0; i < 8; ++i)
    transpose_f32_bf16<<<dim3(32, 32), dim3(32, 8), 0, stream>>>(wsrc[i], wT0 + (long)i * 1048576, 1024, 1024);
  transpose_f32_bf16<<<dim3(128, 32), dim3(32, 8), 0, stream>>>(ffn_w1, w1T, 1024, 4096);
  transpose_f32_bf16<<<dim3(32, 128), dim3(32, 8), 0, stream>>>(ffn_w2, w2T, 4096, 1024);

  // ---- self-attention sub-layer ----
  layernorm_to_bf16<<<dim3(4096), dim3(256), 0, stream>>>(x, ln1_g, ln1_b, lnb);

  qkv_proj<false><<<dim3(32, 8, 3), dim3(256), 0, stream>>>(
      lnb, lnb, wT0, sa_bq, sa_bk, sa_bv, Qh, Kh, VhT);

  attn_softmax_pv<0><<<dim3(32, 64), dim3(512), 0, stream>>>(Qh, Kh, VhT, pmask, attnF1, ctx);

  init_bias_res<<<dim3(4096), dim3(256), 0, stream>>>(x, sa_bo, out1, 1048576);
  gemm_bt<128, 128, EPI_ATOMIC><<<dim3(32, 8, 2), dim3(256), 0, stream>>>(
      ctx, 512L, 1024, wT0 + 3L * 1048576, 512L, 1024, nullptr, nullptr, out1, 4096, 1024, 512);

  // ---- cross-attention sub-layer ----
  layernorm_to_bf16<<<dim3(4096), dim3(256), 0, stream>>>(out1, ln2_g, ln2_b, lnb);

  qkv_proj<true><<<dim3(32, 8, 3), dim3(256), 0, stream>>>(
      lnb, ybf, wT0 + 4L * 1048576, ca_bq, ca_bk, ca_bv, Qh, Kh, VhT);

  attn_softmax_pv<1><<<dim3(32, 64), dim3(512), 0, stream>>>(Qh, Kh, VhT, cmask, attnF2, ctx);

  init_bias_res<<<dim3(4096), dim3(256), 0, stream>>>(out1, ca_bo, out2, 1048576);
  gemm_bt<128, 128, EPI_ATOMIC><<<dim3(32, 8, 2), dim3(256), 0, stream>>>(
      ctx, 512L, 1024, wT0 + 7L * 1048576, 512L, 1024, nullptr, nullptr, out2, 4096, 1024, 512);

  // ---- FFN sub-layer ----
  layernorm_to_bf16<<<dim3(4096), dim3(256), 0, stream>>>(out2, ln3_g, ln3_b, lnb);

  gemm_bt<128, 128, EPI_BF16RELU><<<dim3(32, 32, 1), dim3(256), 0, stream>>>(
      lnb, 0L, 1024, w1T, 0L, 1024, ffn_b1, nullptr, hbuf, 4096, 4096, 1024);

  init_bias_res<<<dim3(4096), dim3(256), 0, stream>>>(out2, ffn_b2, out0, 1048576);
  gemm_bt<128, 128, EPI_ATOMIC><<<dim3(32, 8, 4), dim3(256), 0, stream>>>(
      hbuf, 1024L, 4096, w2T, 1024L, 4096, nullptr, nullptr, out0, 4096, 1024, 1024);
}

// Round 4
// 1084.610 us; speedup vs baseline: 1.2965x; 1.1173x over previous
//
#include <hip/hip_runtime.h>
#include <stdint.h>

// ---------------------------------------------------------------------------
// DecoderLayer (B=4, SQ=SK=1024, D=1024, H=16, depth=64, DFF=4096) on gfx950.
// R3: counted-vmcnt 4-buffer pipelined GEMMs (no per-K-step drain), split-K
//     via partial buffers + fused reduce+LN (no atomics), XCD-rectangle
//     block remap for L2 locality.
// ---------------------------------------------------------------------------

typedef __attribute__((ext_vector_type(8))) short bf16x8;
typedef __attribute__((ext_vector_type(4))) float f32x4;

typedef const void __attribute__((address_space(1)))* gas_ptr;
typedef void __attribute__((address_space(3)))* las_ptr;

__device__ __forceinline__ ushort f2bf(float f) {
  union { float f; uint32_t u; } x; x.f = f;
  uint32_t r = x.u + 0x7fffu + ((x.u >> 16) & 1u);
  return (ushort)(r >> 16);
}

// ---------------- elementwise convert / transpose / layernorm --------------

__global__ __launch_bounds__(256) void convert_f32_bf16(const float* __restrict__ src,
                                                        ushort* __restrict__ dst, int n4) {
  int i = blockIdx.x * 256 + threadIdx.x;
  if (i < n4) {
    float4 v = ((const float4*)src)[i];
    ushort4 o;
    o.x = f2bf(v.x); o.y = f2bf(v.y); o.z = f2bf(v.z); o.w = f2bf(v.w);
    ((ushort4*)dst)[i] = o;
  }
}

struct Ptr8 { const float* p[8]; };

// 8x [1024][1024] f32 -> [1024][1024] bf16 transposed; z selects matrix
__global__ __launch_bounds__(256) void transpose8_f32_bf16(Ptr8 srcs, ushort* __restrict__ dst) {
  __shared__ ushort tile[32][33];
  const float* src = srcs.p[blockIdx.z];
  ushort* d = dst + (long)blockIdx.z * 1048576;
  int c0 = blockIdx.x * 32, r0 = blockIdx.y * 32;
  int tx = threadIdx.x, ty = threadIdx.y;
  for (int i = ty; i < 32; i += 8)
    tile[i][tx] = f2bf(src[(long)(r0 + i) * 1024 + c0 + tx]);
  __syncthreads();
  for (int i = ty; i < 32; i += 8)
    d[(long)(c0 + i) * 1024 + r0 + tx] = tile[tx][i];
}

// src [R][C] f32  ->  dst [C][R] bf16   (block (32,8), grid (C/32, R/32))
__global__ __launch_bounds__(256) void transpose_f32_bf16(const float* __restrict__ src,
                                                          ushort* __restrict__ dst,
                                                          int R, int C) {
  __shared__ ushort tile[32][33];
  int c0 = blockIdx.x * 32, r0 = blockIdx.y * 32;
  int tx = threadIdx.x, ty = threadIdx.y;
  for (int i = ty; i < 32; i += 8)
    tile[i][tx] = f2bf(src[(long)(r0 + i) * C + c0 + tx]);
  __syncthreads();
  for (int i = ty; i < 32; i += 8)
    dst[(long)(c0 + i) * R + r0 + tx] = tile[tx][i];
}

// one row (1024 f32) per block, 256 threads x float4
__global__ __launch_bounds__(256) void layernorm_to_bf16(const float* __restrict__ x,
                                                         const float* __restrict__ gamma,
                                                         const float* __restrict__ beta,
                                                         ushort* __restrict__ out) {
  const int row = blockIdx.x;
  const int t = threadIdx.x, lane = t & 63, w = t >> 6;
  float4 v = ((const float4*)(x + (long)row * 1024))[t];
  float s = v.x + v.y + v.z + v.w;
#pragma unroll
  for (int off = 32; off >= 1; off >>= 1) s += __shfl_xor(s, off);
  __shared__ float r1[4], r2[4];
  if (lane == 0) r1[w] = s;
  __syncthreads();
  const float mu = (r1[0] + r1[1] + r1[2] + r1[3]) * (1.f / 1024.f);
  const float dx = v.x - mu, dy = v.y - mu, dz = v.z - mu, dw = v.w - mu;
  float q = dx * dx + dy * dy + dz * dz + dw * dw;
#pragma unroll
  for (int off = 32; off >= 1; off >>= 1) q += __shfl_xor(q, off);
  if (lane == 0) r2[w] = q;
  __syncthreads();
  const float var = (r2[0] + r2[1] + r2[2] + r2[3]) * (1.f / 1024.f);
  const float is = rsqrtf(var + 1e-6f);
  float4 g4 = ((const float4*)gamma)[t];
  float4 b4 = ((const float4*)beta)[t];
  ushort4 o;
  o.x = f2bf(dx * is * g4.x + b4.x);
  o.y = f2bf(dy * is * g4.y + b4.y);
  o.z = f2bf(dz * is * g4.z + b4.z);
  o.w = f2bf(dw * is * g4.w + b4.w);
  ((ushort4*)(out + (long)row * 1024))[t] = o;
}

// ------------- split-K reduce (+bias+residual) with optional fused LN -------
// one row (1024 f32) per block. outres = res + bias + sum(partials);
// if DO_LN: outln = LN(outres; g,b) in bf16.
template <int NP, bool DO_LN>
__global__ __launch_bounds__(256) void reduce_ln(const float* __restrict__ part,
                                                 const float* __restrict__ res,
                                                 const float* __restrict__ bias,
                                                 const float* __restrict__ g,
                                                 const float* __restrict__ b,
                                                 float* __restrict__ outres,
                                                 ushort* __restrict__ outln) {
  const int row = blockIdx.x;
  const int t = threadIdx.x, lane = t & 63, w = t >> 6;
  const long base = (long)row * 256 + t;  // float4 index
  float4 v = ((const float4*)res)[base];
  float4 bi = ((const float4*)bias)[t];
  v.x += bi.x; v.y += bi.y; v.z += bi.z; v.w += bi.w;
#pragma unroll
  for (int p = 0; p < NP; ++p) {
    float4 pv = ((const float4*)part)[(long)p * 1048576 + base];
    v.x += pv.x; v.y += pv.y; v.z += pv.z; v.w += pv.w;
  }
  ((float4*)outres)[base] = v;
  if constexpr (DO_LN) {
    float s = v.x + v.y + v.z + v.w;
#pragma unroll
    for (int off = 32; off >= 1; off >>= 1) s += __shfl_xor(s, off);
    __shared__ float r1[4], r2[4];
    if (lane == 0) r1[w] = s;
    __syncthreads();
    const float mu = (r1[0] + r1[1] + r1[2] + r1[3]) * (1.f / 1024.f);
    const float dx = v.x - mu, dy = v.y - mu, dz = v.z - mu, dw = v.w - mu;
    float q = dx * dx + dy * dy + dz * dz + dw * dw;
#pragma unroll
    for (int off = 32; off >= 1; off >>= 1) q += __shfl_xor(q, off);
    if (lane == 0) r2[w] = q;
    __syncthreads();
    const float var = (r2[0] + r2[1] + r2[2] + r2[3]) * (1.f / 1024.f);
    const float is = rsqrtf(var + 1e-6f);
    float4 g4 = ((const float4*)g)[t];
    float4 b4 = ((const float4*)b)[t];
    ushort4 o;
    o.x = f2bf(dx * is * g4.x + b4.x);
    o.y = f2bf(dy * is * g4.y + b4.y);
    o.z = f2bf(dz * is * g4.z + b4.z);
    o.w = f2bf(dw * is * g4.w + b4.w);
    ((ushort4*)outln)[base] = o;
  }
}

// ------------------------ XCD-rectangle block remap -------------------------
// Assumes flat block id round-robins over 8 XCDs. Each XCD gets a contiguous
// (GX/MS) x (GY/NS) rectangle of tiles -> small working set per XCD L2.
template <int MS, int NS>
__device__ __forceinline__ void xcd_map(int& mi, int& ni) {
  const int GX = gridDim.x;
  const int bid = blockIdx.x + GX * blockIdx.y;
  const int xcd = bid & 7, idx = bid >> 3;
  const int mw = GX / MS;
  mi = (xcd % MS) * mw + idx % mw;
  ni = (xcd / MS) * (gridDim.y / NS) + idx / mw;
}

// ---------------------------- GEMM (B^T form) ------------------------------
// C[M,N] = A[M,K] @ B^T[N,K]^T, bf16 in, f32 acc. 4 waves (2x2), 128x128 tile,
// BK=32, 4 LDS buffers, 3-deep counted-vmcnt pipeline (loads for tiles t+1,
// t+2 stay in flight across barriers; never drain to 0 in the main loop).

constexpr int EPI_BF16RELU = 0;  // bf16 out with ReLU (+bias)
constexpr int EPI_PARTIAL = 1;   // f32 partial store to outv + z*M*N

template <int BM, int BN, int EPI, int MS, int NS>
__global__ __launch_bounds__(256) void gemm_bt(const ushort* __restrict__ Aall, long sAz, int lda,
                                               const ushort* __restrict__ Ball, long sBz, int ldb,
                                               const float* __restrict__ bias,
                                               void* __restrict__ outv,
                                               int M, int N, int K) {
  constexpr int BK = 32;
  constexpr int WM = BM / 2, WN = BN / 2;
  constexpr int MR = WM / 16, NR = WN / 16;
  constexpr int ACH = BM * BK / 8;
  constexpr int BCH = BN * BK / 8;
  constexpr int BUFSZ = (BM + BN) * BK;  // ushorts
  static_assert((ACH + BCH) / 256 == 4, "LPT must be 4 for vmcnt constants");

  const int z = blockIdx.z;
  const ushort* A = Aall + (long)z * sAz;
  const ushort* B = Ball + (long)z * sBz;
  int mi, ni;
  xcd_map<MS, NS>(mi, ni);
  const int m0 = mi * BM;
  const int n0 = ni * BN;

  __shared__ ushort lds[4 * BUFSZ];

  const int t = threadIdx.x;
  const int lane = t & 63;
  const int w = t >> 6;
  const int wr = w >> 1, wc = w & 1;
  const int g = lane >> 4, rl = lane & 15;
  const int cbase = t & ~63;

  f32x4 acc[MR][NR];
#pragma unroll
  for (int i = 0; i < MR; ++i)
#pragma unroll
    for (int j = 0; j < NR; ++j) {
      f32x4 zv = {0.f, 0.f, 0.f, 0.f};
      acc[i][j] = zv;
    }

  auto stage = [&](int buf, int kt) {
    const int k0 = kt * BK;
    ushort* lb = &lds[buf * BUFSZ];
#pragma unroll
    for (int j = 0; j < 2; ++j) {
      const int c = j * 256 + t;
      const int row = c >> 2, pos = c & 3;
      const int kg = pos ^ (row & 3);  // source-address swizzle
      const ushort* src = A + (long)(m0 + row) * lda + k0 + kg * 8;
      __builtin_amdgcn_global_load_lds((gas_ptr)src, (las_ptr)&lb[(j * 256 + cbase) * 8], 16, 0, 0);
    }
#pragma unroll
    for (int j = 0; j < 2; ++j) {
      const int c = j * 256 + t;
      const int row = c >> 2, pos = c & 3;
      const int kg = pos ^ (row & 3);
      const ushort* src = B + (long)(n0 + row) * ldb + k0 + kg * 8;
      __builtin_amdgcn_global_load_lds((gas_ptr)src, (las_ptr)&lb[BM * BK + (j * 256 + cbase) * 8], 16, 0, 0);
    }
  };

  const int nt = K / BK;
  stage(0, 0);
  if (nt > 1) stage(1, 1);
  if (nt > 2) stage(2, 2);

  for (int kt = 0; kt < nt; ++kt) {
    const int rem = nt - 1 - kt;
    if (rem >= 2)      asm volatile("s_waitcnt vmcnt(8)" ::: "memory");
    else if (rem == 1) asm volatile("s_waitcnt vmcnt(4)" ::: "memory");
    else               asm volatile("s_waitcnt vmcnt(0)" ::: "memory");
    __builtin_amdgcn_s_barrier();
    asm volatile("" ::: "memory");
    const ushort* buf = &lds[(kt & 3) * BUFSZ];
    bf16x8 af[MR], bfr[NR];
#pragma unroll
    for (int i = 0; i < MR; ++i) {
      const int row = wr * WM + i * 16 + rl;
      af[i] = *(const bf16x8*)&buf[row * BK + ((g ^ (row & 3)) * 8)];
    }
#pragma unroll
    for (int j = 0; j < NR; ++j) {
      const int row = wc * WN + j * 16 + rl;
      bfr[j] = *(const bf16x8*)&buf[BM * BK + row * BK + ((g ^ (row & 3)) * 8)];
    }
#pragma unroll
    for (int i = 0; i < MR; ++i)
#pragma unroll
      for (int j = 0; j < NR; ++j)
        acc[i][j] = __builtin_amdgcn_mfma_f32_16x16x32_bf16(af[i], bfr[j], acc[i][j], 0, 0, 0);
    asm volatile("s_waitcnt lgkmcnt(0)" ::: "memory");
    __builtin_amdgcn_s_barrier();
    asm volatile("" ::: "memory");
    if (kt + 3 < nt) stage((kt + 3) & 3, kt + 3);
  }

#pragma unroll
  for (int i = 0; i < MR; ++i) {
#pragma unroll
    for (int j = 0; j < NR; ++j) {
#pragma unroll
      for (int e = 0; e < 4; ++e) {
        const int row = m0 + wr * WM + i * 16 + g * 4 + e;
        const int col = n0 + wc * WN + j * 16 + rl;
        float v = acc[i][j][e];
        if constexpr (EPI == EPI_BF16RELU) {
          v += bias[col];
          ((ushort*)outv)[(long)row * N + col] = f2bf(v < 0.f ? 0.f : v);
        } else {
          ((float*)outv)[(long)z * M * N + (long)row * N + col] = v;
        }
      }
    }
  }
}

// ----------------------- fused QKV projection ------------------------------
// grid (32, 8, 3): z=0 -> Q, z=1 -> K (split-heads), z=2 -> V (V^T store).

template <bool CROSS>
__global__ __launch_bounds__(256) void qkv_proj(const ushort* __restrict__ Aq,
                                                const ushort* __restrict__ Akv,
                                                const ushort* __restrict__ Wt,
                                                const float* __restrict__ bq,
                                                const float* __restrict__ bk,
                                                const float* __restrict__ bv,
                                                ushort* __restrict__ Qh,
                                                ushort* __restrict__ Kh,
                                                ushort* __restrict__ VhT) {
  constexpr int BM = 128, BN = 128, BK = 32;
  constexpr int MR = 4, NR = 4;
  constexpr int BUFSZ = (BM + BN) * BK;

  const int z = blockIdx.z;
  const ushort* A = (CROSS && z > 0) ? Akv : Aq;
  const ushort* B = Wt + (long)z * 1048576;
  const float* bias = (z == 0) ? bq : (z == 1) ? bk : bv;
  int mi, ni;
  xcd_map<4, 2>(mi, ni);
  const int m0 = mi * BM;
  const int n0 = ni * BN;

  __shared__ ushort lds[4 * BUFSZ];

  const int t = threadIdx.x;
  const int lane = t & 63;
  const int w = t >> 6;
  const int wr = w >> 1, wc = w & 1;
  const int g = lane >> 4, rl = lane & 15;
  const int cbase = t & ~63;

  f32x4 acc[MR][NR];
#pragma unroll
  for (int i = 0; i < MR; ++i)
#pragma unroll
    for (int j = 0; j < NR; ++j) {
      f32x4 zv = {0.f, 0.f, 0.f, 0.f};
      acc[i][j] = zv;
    }

  auto stage = [&](int buf, int kt) {
    const int k0 = kt * BK;
    ushort* lb = &lds[buf * BUFSZ];
#pragma unroll
    for (int j = 0; j < 2; ++j) {
      const int c = j * 256 + t;
      const int row = c >> 2, pos = c & 3;
      const int kg = pos ^ (row & 3);
      const ushort* src = A + (long)(m0 + row) * 1024 + k0 + kg * 8;
      __builtin_amdgcn_global_load_lds((gas_ptr)src, (las_ptr)&lb[(j * 256 + cbase) * 8], 16, 0, 0);
    }
#pragma unroll
    for (int j = 0; j < 2; ++j) {
      const int c = j * 256 + t;
      const int row = c >> 2, pos = c & 3;
      const int kg = pos ^ (row & 3);
      const ushort* src = B + (long)(n0 + row) * 1024 + k0 + kg * 8;
      __builtin_amdgcn_global_load_lds((gas_ptr)src, (las_ptr)&lb[BM * BK + (j * 256 + cbase) * 8], 16, 0, 0);
    }
  };

  stage(0, 0);
  stage(1, 1);
  stage(2, 2);

  for (int kt = 0; kt < 32; ++kt) {
    const int rem = 31 - kt;
    if (rem >= 2)      asm volatile("s_waitcnt vmcnt(8)" ::: "memory");
    else if (rem == 1) asm volatile("s_waitcnt vmcnt(4)" ::: "memory");
    else               asm volatile("s_waitcnt vmcnt(0)" ::: "memory");
    __builtin_amdgcn_s_barrier();
    asm volatile("" ::: "memory");
    const ushort* buf = &lds[(kt & 3) * BUFSZ];
    bf16x8 af[MR], bfr[NR];
#pragma unroll
    for (int i = 0; i < MR; ++i) {
      const int row = wr * 64 + i * 16 + rl;
      af[i] = *(const bf16x8*)&buf[row * BK + ((g ^ (row & 3)) * 8)];
    }
#pragma unroll
    for (int j = 0; j < NR; ++j) {
      const int row = wc * 64 + j * 16 + rl;
      bfr[j] = *(const bf16x8*)&buf[BM * BK + row * BK + ((g ^ (row & 3)) * 8)];
    }
#pragma unroll
    for (int i = 0; i < MR; ++i)
#pragma unroll
      for (int j = 0; j < NR; ++j)
        acc[i][j] = __builtin_amdgcn_mfma_f32_16x16x32_bf16(af[i], bfr[j], acc[i][j], 0, 0, 0);
    asm volatile("s_waitcnt lgkmcnt(0)" ::: "memory");
    __builtin_amdgcn_s_barrier();
    asm volatile("" ::: "memory");
    if (kt + 3 < 32) stage((kt + 3) & 3, kt + 3);
  }

  ushort* out = (z == 0) ? Qh : (z == 1) ? Kh : VhT;
#pragma unroll
  for (int i = 0; i < MR; ++i) {
#pragma unroll
    for (int j = 0; j < NR; ++j) {
      const int row0 = m0 + wr * 64 + i * 16 + g * 4;
      const int col = n0 + wc * 64 + j * 16 + rl;
      const int b = row0 >> 10, h = col >> 6, d = col & 63;
      if (z == 2) {  // V^T: 4 consecutive s per lane -> ushort4 store
        ushort4 pk;
        pk.x = f2bf(acc[i][j][0] + bias[col]);
        pk.y = f2bf(acc[i][j][1] + bias[col]);
        pk.z = f2bf(acc[i][j][2] + bias[col]);
        pk.w = f2bf(acc[i][j][3] + bias[col]);
        *(ushort4*)&out[((long)(b * 16 + h) * 64 + d) * 1024 + (row0 & 1023)] = pk;
      } else {
#pragma unroll
        for (int e = 0; e < 4; ++e) {
          const int s = (row0 + e) & 1023;
          out[(((long)(b * 16 + h) * 1024) + s) * 64 + d] = f2bf(acc[i][j][e] + bias[col]);
        }
      }
    }
  }
}

// -------------- fused scores + softmax + PV (per 32 q-rows) ----------------
// grid (32, 64), block 512 (8 waves). Wave w: cols [w*128, w*128+128).

__device__ __forceinline__ int p_off(int r, int p) {  // ushort offset of 16B chunk
  return (r * 128 + (p ^ (r & 7))) * 8;
}

template <int MODE>  // 0: 2-D padding mask [SQ,SQ]; 1: per-col mask [SK]
__global__ __launch_bounds__(512) void attn_softmax_pv(const ushort* __restrict__ Q,
                                                       const ushort* __restrict__ Kh,
                                                       const ushort* __restrict__ VhT,
                                                       const float* __restrict__ mask,
                                                       float* __restrict__ outF,
                                                       ushort* __restrict__ ctx) {
  // XCD remap: each XCD owns 8 consecutive bh panels (K/V stay in its L2)
  const int bid = blockIdx.x + 32 * blockIdx.y;
  const int xcd = bid & 7, idx = bid >> 3;
  const int q0 = (idx & 31) * 32;
  const int bh = xcd * 8 + (idx >> 5);

  const int t = threadIdx.x, lane = t & 63, w = t >> 6;
  const int g = lane >> 4, rl = lane & 15;
  const ushort* Qb = Q + (long)bh * 65536;
  const ushort* Kb = Kh + (long)bh * 65536;
  const ushort* Vb = VhT + (long)bh * 65536;

  __shared__ ushort Pl[32768];  // 64 KB: P tile (bf16, swizzled) then f32 partials
  __shared__ float redm[8][32];
  __shared__ float reds[8][32];

  bf16x8 qa[2][2];
#pragma unroll
  for (int rb = 0; rb < 2; ++rb)
#pragma unroll
    for (int kk = 0; kk < 2; ++kk)
      qa[rb][kk] = *(const bf16x8*)(Qb + (long)(q0 + rb * 16 + rl) * 64 + kk * 32 + g * 8);

  f32x4 acc[2][8];
#pragma unroll
  for (int rb = 0; rb < 2; ++rb)
#pragma unroll
    for (int nf = 0; nf < 8; ++nf) {
      f32x4 zv = {0.f, 0.f, 0.f, 0.f};
      acc[rb][nf] = zv;
    }

  const int c0 = w * 128;
#pragma unroll
  for (int nf = 0; nf < 8; ++nf) {
    const ushort* kp = Kb + (long)(c0 + nf * 16 + rl) * 64 + g * 8;
    bf16x8 k0 = *(const bf16x8*)(kp);
    bf16x8 k1 = *(const bf16x8*)(kp + 32);
#pragma unroll
    for (int rb = 0; rb < 2; ++rb) {
      acc[rb][nf] = __builtin_amdgcn_mfma_f32_16x16x32_bf16(qa[rb][0], k0, acc[rb][nf], 0, 0, 0);
      acc[rb][nf] = __builtin_amdgcn_mfma_f32_16x16x32_bf16(qa[rb][1], k1, acc[rb][nf], 0, 0, 0);
    }
  }

  // scale + mask
#pragma unroll
  for (int rb = 0; rb < 2; ++rb)
#pragma unroll
    for (int nf = 0; nf < 8; ++nf)
#pragma unroll
      for (int e = 0; e < 4; ++e) {
        const int r = q0 + rb * 16 + g * 4 + e;
        const int c = c0 + nf * 16 + rl;
        float mv;
        if constexpr (MODE == 0) mv = mask[(long)r * 1024 + c];
        else mv = mask[c];
        acc[rb][nf][e] = acc[rb][nf][e] * 0.125f + mv * (-1e9f);
      }

  // row max
  float mrow[2][4];
#pragma unroll
  for (int rb = 0; rb < 2; ++rb)
#pragma unroll
    for (int e = 0; e < 4; ++e) {
      float m = acc[rb][0][e];
#pragma unroll
      for (int nf = 1; nf < 8; ++nf) m = fmaxf(m, acc[rb][nf][e]);
#pragma unroll
      for (int off = 8; off >= 1; off >>= 1) m = fmaxf(m, __shfl_xor(m, off));
      mrow[rb][e] = m;
    }
  if (rl == 0)
#pragma unroll
    for (int rb = 0; rb < 2; ++rb)
#pragma unroll
      for (int e = 0; e < 4; ++e) redm[w][rb * 16 + g * 4 + e] = mrow[rb][e];
  __syncthreads();
  float mfin[2][4];
#pragma unroll
  for (int rb = 0; rb < 2; ++rb)
#pragma unroll
    for (int e = 0; e < 4; ++e) {
      const int r = rb * 16 + g * 4 + e;
      float m = redm[0][r];
#pragma unroll
      for (int ww = 1; ww < 8; ++ww) m = fmaxf(m, redm[ww][r]);
      mfin[rb][e] = m;
    }

  // exp + row sum
  float srow[2][4];
#pragma unroll
  for (int rb = 0; rb < 2; ++rb)
#pragma unroll
    for (int e = 0; e < 4; ++e) {
      float s = 0.f;
#pragma unroll
      for (int nf = 0; nf < 8; ++nf) {
        float p = exp2f((acc[rb][nf][e] - mfin[rb][e]) * 1.44269504088896340736f);
        acc[rb][nf][e] = p;
        s += p;
      }
#pragma unroll
      for (int off = 8; off >= 1; off >>= 1) s += __shfl_xor(s, off);
      srow[rb][e] = s;
    }
  if (rl == 0)
#pragma unroll
    for (int rb = 0; rb < 2; ++rb)
#pragma unroll
      for (int e = 0; e < 4; ++e) reds[w][rb * 16 + g * 4 + e] = srow[rb][e];
  __syncthreads();

  // normalize, write f32 attn to d_out, and bf16 P to swizzled LDS
#pragma unroll
  for (int rb = 0; rb < 2; ++rb)
#pragma unroll
    for (int e = 0; e < 4; ++e) {
      const int r = rb * 16 + g * 4 + e;
      float s = 0.f;
#pragma unroll
      for (int ww = 0; ww < 8; ++ww) s += reds[ww][r];
      const float inv = 1.0f / s;
      const long rowoff = (long)bh * 1048576 + (long)(q0 + r) * 1024;
#pragma unroll
      for (int nf = 0; nf < 8; ++nf) {
        const int c = c0 + nf * 16 + rl;
        const float p = acc[rb][nf][e] * inv;
        outF[rowoff + c] = p;
        Pl[p_off(r, c >> 3) + (c & 7)] = f2bf(p);
      }
    }
  __syncthreads();

  // PV partial: wave w covers K-strip [c0, c0+128)
  f32x4 acc2[2][4];
#pragma unroll
  for (int rb = 0; rb < 2; ++rb)
#pragma unroll
    for (int j = 0; j < 4; ++j) {
      f32x4 zv = {0.f, 0.f, 0.f, 0.f};
      acc2[rb][j] = zv;
    }
#pragma unroll
  for (int s = 0; s < 4; ++s) {
    const int kb = c0 + s * 32;
    bf16x8 a[2];
#pragma unroll
    for (int rb = 0; rb < 2; ++rb)
      a[rb] = *(const bf16x8*)&Pl[p_off(rb * 16 + rl, (kb >> 3) + g)];
#pragma unroll
    for (int j = 0; j < 4; ++j) {
      bf16x8 b = *(const bf16x8*)(Vb + (long)(j * 16 + rl) * 1024 + kb + g * 8);
#pragma unroll
      for (int rb = 0; rb < 2; ++rb)
        acc2[rb][j] = __builtin_amdgcn_mfma_f32_16x16x32_bf16(a[rb], b, acc2[rb][j], 0, 0, 0);
    }
  }
  __syncthreads();  // all P reads done before partials overwrite Pl

  float* Pred = (float*)Pl;  // [8][32*64]
#pragma unroll
  for (int rb = 0; rb < 2; ++rb)
#pragma unroll
    for (int j = 0; j < 4; ++j)
#pragma unroll
      for (int e = 0; e < 4; ++e) {
        const int r = rb * 16 + g * 4 + e;
        const int d = j * 16 + rl;
        Pred[w * 2048 + r * 64 + d] = acc2[rb][j][e];
      }
  __syncthreads();

  const int bb = bh >> 4, hh = bh & 15;
#pragma unroll
  for (int i = t; i < 2048; i += 512) {
    float s = 0.f;
#pragma unroll
    for (int ww = 0; ww < 8; ++ww) s += Pred[ww * 2048 + i];
    const int r = i >> 6, d = i & 63;
    ctx[((long)bb * 1024 + q0 + r) * 1024 + hh * 64 + d] = f2bf(s);
  }
}

// ---------------------------------------------------------------------------

extern "C" void kernel_launch(void* const* d_in, const int* in_sizes, int n_in,
                              void* d_out, int out_size, void* d_ws, size_t ws_size,
                              hipStream_t stream) {
  (void)in_sizes; (void)n_in; (void)out_size; (void)ws_size;

  const float* x     = (const float*)d_in[0];
  const float* y     = (const float*)d_in[1];
  const float* cmask = (const float*)d_in[2];
  const float* pmask = (const float*)d_in[3];
  const float* sa_wq = (const float*)d_in[4];
  const float* sa_bq = (const float*)d_in[5];
  const float* sa_wk = (const float*)d_in[6];
  const float* sa_bk = (const float*)d_in[7];
  const float* sa_wv = (const float*)d_in[8];
  const float* sa_bv = (const float*)d_in[9];
  const float* sa_wo = (const float*)d_in[10];
  const float* sa_bo = (const float*)d_in[11];
  const float* ca_wq = (const float*)d_in[12];
  const float* ca_bq = (const float*)d_in[13];
  const float* ca_wk = (const float*)d_in[14];
  const float* ca_bk = (const float*)d_in[15];
  const float* ca_wv = (const float*)d_in[16];
  const float* ca_bv = (const float*)d_in[17];
  const float* ca_wo = (const float*)d_in[18];
  const float* ca_bo = (const float*)d_in[19];
  const float* ffn_w1 = (const float*)d_in[20];
  const float* ffn_b1 = (const float*)d_in[21];
  const float* ffn_w2 = (const float*)d_in[22];
  const float* ffn_b2 = (const float*)d_in[23];
  const float* ln1_g = (const float*)d_in[24];
  const float* ln1_b = (const float*)d_in[25];
  const float* ln2_g = (const float*)d_in[26];
  const float* ln2_b = (const float*)d_in[27];
  const float* ln3_g = (const float*)d_in[28];
  const float* ln3_b = (const float*)d_in[29];

  char* ws = (char*)d_ws;
  ushort* wT0 = (ushort*)(ws + 0);             // 8 x [1024][1024] bf16 (W^T)
  ushort* w1T = (ushort*)(ws + (16L << 20));   // [4096][1024]
  ushort* w2T = (ushort*)(ws + (24L << 20));   // [1024][4096]
  ushort* ybf = (ushort*)(ws + (32L << 20));   // y bf16
  ushort* lnb = (ushort*)(ws + (40L << 20));   // LN output bf16 (reused x3)
  ushort* Qh  = (ushort*)(ws + (48L << 20));   // [BH][1024][64]
  ushort* Kh  = (ushort*)(ws + (56L << 20));   // [BH][1024][64]
  ushort* VhT = (ushort*)(ws + (64L << 20));   // [BH][64][1024]
  ushort* ctx = (ushort*)(ws + (72L << 20));   // [4096][1024] bf16
  float*  out1 = (float*)(ws + (80L << 20));   // residual stream after SA
  float*  out2 = (float*)(ws + (96L << 20));   // residual stream after CA
  ushort* hbuf = (ushort*)(ws + (112L << 20)); // FFN hidden [4096][4096] bf16
  float*  part = (float*)(ws + (152L << 20));  // split-K partials, up to 4x16.8MB

  float* out0   = (float*)d_out;
  float* attnF1 = out0 + 4194304;    // dec_attn     [4,16,1024,1024]
  float* attnF2 = out0 + 71303168;   // dec_enc_attn [4,16,1024,1024]

  // ---- weight/activation conversions ----
  convert_f32_bf16<<<dim3(4096), dim3(256), 0, stream>>>(y, ybf, 1048576);
  Ptr8 w8 = {{sa_wq, sa_wk, sa_wv, sa_wo, ca_wq, ca_wk, ca_wv, ca_wo}};
  transpose8_f32_bf16<<<dim3(32, 32, 8), dim3(32, 8), 0, stream>>>(w8, wT0);
  transpose_f32_bf16<<<dim3(128, 32), dim3(32, 8), 0, stream>>>(ffn_w1, w1T, 1024, 4096);
  transpose_f32_bf16<<<dim3(32, 128), dim3(32, 8), 0, stream>>>(ffn_w2, w2T, 4096, 1024);

  // ---- self-attention sub-layer ----
  layernorm_to_bf16<<<dim3(4096), dim3(256), 0, stream>>>(x, ln1_g, ln1_b, lnb);

  qkv_proj<false><<<dim3(32, 8, 3), dim3(256), 0, stream>>>(
      lnb, lnb, wT0, sa_bq, sa_bk, sa_bv, Qh, Kh, VhT);

  attn_softmax_pv<0><<<dim3(32, 64), dim3(512), 0, stream>>>(Qh, Kh, VhT, pmask, attnF1, ctx);

  gemm_bt<128, 128, EPI_PARTIAL, 4, 2><<<dim3(32, 8, 2), dim3(256), 0, stream>>>(
      ctx, 512L, 1024, wT0 + 3L * 1048576, 512L, 1024, nullptr, part, 4096, 1024, 512);
  reduce_ln<2, true><<<dim3(4096), dim3(256), 0, stream>>>(
      part, x, sa_bo, ln2_g, ln2_b, out1, lnb);

  // ---- cross-attention sub-layer ----
  qkv_proj<true><<<dim3(32, 8, 3), dim3(256), 0, stream>>>(
      lnb, ybf, wT0 + 4L * 1048576, ca_bq, ca_bk, ca_bv, Qh, Kh, VhT);

  attn_softmax_pv<1><<<dim3(32, 64), dim3(512), 0, stream>>>(Qh, Kh, VhT, cmask, attnF2, ctx);

  gemm_bt<128, 128, EPI_PARTIAL, 4, 2><<<dim3(32, 8, 2), dim3(256), 0, stream>>>(
      ctx, 512L, 1024, wT0 + 7L * 1048576, 512L, 1024, nullptr, part, 4096, 1024, 512);
  reduce_ln<2, true><<<dim3(4096), dim3(256), 0, stream>>>(
      part, out1, ca_bo, ln3_g, ln3_b, out2, lnb);

  // ---- FFN sub-layer ----
  gemm_bt<128, 128, EPI_BF16RELU, 2, 4><<<dim3(32, 32, 1), dim3(256), 0, stream>>>(
      lnb, 0L, 1024, w1T, 0L, 1024, ffn_b1, hbuf, 4096, 4096, 1024);

  gemm_bt<128, 128, EPI_PARTIAL, 4, 2><<<dim3(32, 8, 4), dim3(256), 0, stream>>>(
      hbuf, 1024L, 4096, w2T, 1024L, 4096, nullptr, part, 4096, 1024, 1024);
  reduce_ln<4, false><<<dim3(4096), dim3(256), 0, stream>>>(
      part, out2, ffn_b2, nullptr, nullptr, out0, nullptr);
}